// Round 4
// baseline (1135.673 us; speedup 1.0000x reference)
//
#include <hip/hip_runtime.h>
#include <cfloat>

#define NROWS 131072
#define EDIM 256
#define NE 1024

#define BM 128
#define BN 128
#define BK 32

// ---------- numpy pairwise sum-of-squares for one 256-elem contiguous row ----------
__device__ __forceinline__ float np_sumsq256(const float* __restrict__ row) {
    float s[2];
#pragma unroll
    for (int h = 0; h < 2; ++h) {
        const float* a = row + h * 128;
        float r[8];
#pragma unroll
        for (int j = 0; j < 8; ++j) r[j] = __fmul_rn(a[j], a[j]);
        for (int i = 8; i < 128; i += 8) {
#pragma unroll
            for (int j = 0; j < 8; ++j)
                r[j] = __fadd_rn(r[j], __fmul_rn(a[i + j], a[i + j]));
        }
        s[h] = __fadd_rn(__fadd_rn(__fadd_rn(r[0], r[1]), __fadd_rn(r[2], r[3])),
                         __fadd_rn(__fadd_rn(r[4], r[5]), __fadd_rn(r[6], r[7])));
    }
    return __fadd_rn(s[0], s[1]);
}

__global__ __launch_bounds__(256)
void rownorm_kernel(const float* __restrict__ x, float* __restrict__ out, int nrows) {
    int row = blockIdx.x * blockDim.x + threadIdx.x;
    if (row < nrows) out[row] = np_sumsq256(x + (size_t)row * EDIM);
}

// async global->LDS, 16B per lane, linear LDS dest (wave-uniform base + lane*16)
__device__ __forceinline__ void gload_lds16(const float* g, float* lds) {
    __builtin_amdgcn_global_load_lds((const __attribute__((address_space(1))) void*)g,
                                     (__attribute__((address_space(3))) void*)lds,
                                     16, 0, 0);
}

// ---------- main: sequential-FMA chain over k ascending (bit-exact vs round 3),
//            LDS row-major [row][BK] tiles with XOR-swizzled 16B chunks,
//            staged via global_load_lds (swizzle folded into global src addr) ----------
__global__ __launch_bounds__(256, 3)
void vq_main_kernel(const float* __restrict__ z,
                    const float* __restrict__ e,
                    const float* __restrict__ z2g,
                    const float* __restrict__ e2g,
                    float* __restrict__ out_zq,
                    float* __restrict__ out_idx,
                    double* __restrict__ partials) {
    __shared__ __align__(16) float Atile[BM * BK];   // 16 KiB
    __shared__ __align__(16) float Btile[BN * BK];   // 16 KiB
    __shared__ float  e2s[BN];
    __shared__ int    fIdx[BM];
    __shared__ double dred[256];

    const int tid  = threadIdx.x;
    const int m0   = blockIdx.x * BM;
    const int trow = tid >> 4;     // 0..15 -> rows trow*8..+8
    const int tcol = tid & 15;     // 0..15 -> cols tcol*8..+8
    const int keyA = trow & 7;     // swizzle key for all 8 A-rows of this thread
    const int keyB = tcol & 7;     // swizzle key for all 8 B-rows of this thread

    // staging lane mapping: lane covers (row = i*32 + rsub, physical chunk pc)
    const int rsub = tid >> 3;     // 0..31
    const int pc   = tid & 7;      // physical 16B chunk index within row

    size_t gAoff[4], gBoff[4];     // element offsets (row base + swizzled chunk)
#pragma unroll
    for (int i = 0; i < 4; ++i) {
        int r = i * 32 + rsub;                 // 0..127
        int l = pc ^ ((r >> 3) & 7);           // logical chunk at this physical slot
        gAoff[i] = (size_t)(m0 + r) * EDIM + (size_t)(l * 4);
        gBoff[i] = (size_t)r * EDIM + (size_t)(l * 4);   // + n0*EDIM + k0 at use
    }

    float z2r[8];
#pragma unroll
    for (int i = 0; i < 8; ++i) z2r[i] = z2g[m0 + trow * 8 + i];

    float bestV[8];
    int   bestI[8];
#pragma unroll
    for (int i = 0; i < 8; ++i) { bestV[i] = FLT_MAX; bestI[i] = 0; }

#pragma unroll 1
    for (int n0 = 0; n0 < NE; n0 += BN) {
        float acc[8][8];
#pragma unroll
        for (int i = 0; i < 8; ++i)
#pragma unroll
            for (int j = 0; j < 8; ++j) acc[i][j] = 0.f;

#pragma unroll 1
        for (int k0 = 0; k0 < EDIM; k0 += BK) {
            __syncthreads();                       // prev tile readers done
            if (k0 == 0 && tid < BN) e2s[tid] = e2g[n0 + tid];
#pragma unroll
            for (int i = 0; i < 4; ++i) {
                gload_lds16(z + gAoff[i] + k0, &Atile[(i * 256 + tid) * 4]);
                gload_lds16(e + (size_t)n0 * EDIM + gBoff[i] + k0, &Btile[(i * 256 + tid) * 4]);
            }
            asm volatile("s_waitcnt vmcnt(0)" ::: "memory");
            __syncthreads();                       // tile visible to all waves

            const float* Ab = &Atile[trow * (8 * BK)];
            const float* Bb = &Btile[tcol * (8 * BK)];
#pragma unroll 2
            for (int kk = 0; kk < 8; ++kk) {       // 16B chunk = 4 consecutive k
                const float4* bp = reinterpret_cast<const float4*>(Bb + ((kk ^ keyB) << 2));
                float4 b[8];
#pragma unroll
                for (int j = 0; j < 8; ++j) b[j] = bp[j * 8];   // row stride 32 floats
                const float4* ap = reinterpret_cast<const float4*>(Ab + ((kk ^ keyA) << 2));
#pragma unroll
                for (int i = 0; i < 8; ++i) {
                    float4 a = ap[i * 8];
#pragma unroll
                    for (int j = 0; j < 8; ++j) {  // k ascending: x,y,z,w — chain preserved
                        acc[i][j] = __fmaf_rn(a.x, b[j].x, acc[i][j]);
                        acc[i][j] = __fmaf_rn(a.y, b[j].y, acc[i][j]);
                        acc[i][j] = __fmaf_rn(a.z, b[j].z, acc[i][j]);
                        acc[i][j] = __fmaf_rn(a.w, b[j].w, acc[i][j]);
                    }
                }
            }
        }

        // d = fl(fl(z2 + e2) - 2*m); per-thread argmin, ascending col order
#pragma unroll
        for (int i = 0; i < 8; ++i) {
#pragma unroll
            for (int j = 0; j < 8; ++j) {
                int   n = n0 + tcol * 8 + j;
                float d = __fsub_rn(__fadd_rn(z2r[i], e2s[tcol * 8 + j]),
                                    __fmul_rn(2.0f, acc[i][j]));
                if (d < bestV[i]) { bestV[i] = d; bestI[i] = n; }   // strict < keeps lowest idx
            }
        }
    }

    // ---- merge 16 col-group threads per row via LDS (reuse tiles as scratch) ----
    __syncthreads();
    float* red_v = Atile;                             // [BM][16] floats
    int*   red_i = reinterpret_cast<int*>(Btile);     // [BM][16] ints
#pragma unroll
    for (int i = 0; i < 8; ++i) {
        int row = trow * 8 + i;
        red_v[row * 16 + tcol] = bestV[i];
        red_i[row * 16 + tcol] = bestI[i];
    }
    __syncthreads();

    if (tid < BM) {
        const int r = tid;
        float b1 = FLT_MAX; int i1 = 0x7fffffff;
        for (int t = 0; t < 16; ++t) {
            float v  = red_v[r * 16 + t];
            int   id = red_i[r * 16 + t];
            if (v < b1 || (v == b1 && id < i1)) { b1 = v; i1 = id; }
        }
        fIdx[r] = i1;
        out_idx[m0 + r] = (float)i1;
    }
    __syncthreads();

    // ---- z_q_st write + loss partial ----
    double lsum = 0.0;
    for (int r = 0; r < BM; ++r) {
        int   fi = fIdx[r];
        float zv = z[(size_t)(m0 + r) * EDIM + tid];
        float ev = e[(size_t)fi * EDIM + tid];
        float dd = __fsub_rn(ev, zv);                                  // z_q - z (fp32)
        out_zq[(size_t)(m0 + r) * EDIM + tid] = __fadd_rn(zv, dd);     // z + sg(z_q - z)
        lsum += (double)dd * (double)dd;
    }
    dred[tid] = lsum;
    __syncthreads();
#pragma unroll
    for (int s = 128; s > 0; s >>= 1) {
        if (tid < s) dred[tid] += dred[tid + s];
        __syncthreads();
    }
    if (tid == 0) partials[blockIdx.x] = dred[0];
}

// ---------- loss finalize ----------
__global__ void vq_loss_kernel(const double* __restrict__ partials, float* __restrict__ out_loss) {
    __shared__ double s[256];
    const int tid = threadIdx.x;
    double v = 0.0;
    for (int i = tid; i < NROWS / BM; i += 256) v += partials[i];
    s[tid] = v;
    __syncthreads();
    for (int k = 128; k > 0; k >>= 1) {
        if (tid < k) s[tid] += s[tid + k];
        __syncthreads();
    }
    if (tid == 0) {
        double mean = s[0] / ((double)NROWS * (double)EDIM);
        out_loss[0] = (float)(1.25 * mean);   // (1 + BETA) * mean((z_q - z)^2)
    }
}

extern "C" void kernel_launch(void* const* d_in, const int* in_sizes, int n_in,
                              void* d_out, int out_size, void* d_ws, size_t ws_size,
                              hipStream_t stream) {
    (void)n_in; (void)out_size; (void)ws_size;
    const float* z = (const float*)d_in[0];
    const float* e = (const float*)d_in[1];
    if (in_sizes[0] == NE * EDIM) {           // defensive: swap if input order differs
        const float* t = z; z = e; e = t;
    }
    float* out      = (float*)d_out;
    float* out_zq   = out;
    float* out_loss = out + (size_t)NROWS * EDIM;
    float* out_idx  = out_loss + 1;

    float*  z2g      = (float*)d_ws;                          // 512 KiB
    float*  e2g      = (float*)((char*)d_ws + 524288);        // 4 KiB
    double* partials = (double*)((char*)d_ws + 532480);       // 8 KiB

    rownorm_kernel<<<(NROWS + 255) / 256, 256, 0, stream>>>(z, z2g, NROWS);
    rownorm_kernel<<<(NE + 255) / 256, 256, 0, stream>>>(e, e2g, NE);
    vq_main_kernel<<<NROWS / BM, 256, 0, stream>>>(z, e, z2g, e2g, out_zq, out_idx, partials);
    vq_loss_kernel<<<1, 256, 0, stream>>>(partials, out_loss);
}

// Round 5
// 1051.846 us; speedup vs baseline: 1.0797x; 1.0797x over previous
//
#include <hip/hip_runtime.h>
#include <cfloat>

#define NROWS 131072
#define EDIM 256
#define NE 1024

#define BM 128
#define BN 128
#define BK 32

// ---------- numpy pairwise sum-of-squares for one 256-elem contiguous row ----------
__device__ __forceinline__ float np_sumsq256(const float* __restrict__ row) {
    float s[2];
#pragma unroll
    for (int h = 0; h < 2; ++h) {
        const float* a = row + h * 128;
        float r[8];
#pragma unroll
        for (int j = 0; j < 8; ++j) r[j] = __fmul_rn(a[j], a[j]);
        for (int i = 8; i < 128; i += 8) {
#pragma unroll
            for (int j = 0; j < 8; ++j)
                r[j] = __fadd_rn(r[j], __fmul_rn(a[i + j], a[i + j]));
        }
        s[h] = __fadd_rn(__fadd_rn(__fadd_rn(r[0], r[1]), __fadd_rn(r[2], r[3])),
                         __fadd_rn(__fadd_rn(r[4], r[5]), __fadd_rn(r[6], r[7])));
    }
    return __fadd_rn(s[0], s[1]);
}

__global__ __launch_bounds__(256)
void rownorm_kernel(const float* __restrict__ x, float* __restrict__ out, int nrows) {
    int row = blockIdx.x * blockDim.x + threadIdx.x;
    if (row < nrows) out[row] = np_sumsq256(x + (size_t)row * EDIM);
}

// async global->LDS, 16B per lane, linear LDS dest (wave-uniform base + lane*16)
__device__ __forceinline__ void gload_lds16(const float* g, float* lds) {
    __builtin_amdgcn_global_load_lds((const __attribute__((address_space(1))) void*)g,
                                     (__attribute__((address_space(3))) void*)lds,
                                     16, 0, 0);
}

// ---------- main: sequential-FMA chain over k ascending (bit-exact vs round 3),
//            LDS row-major [row][BK] tiles, XOR-swizzled 16B chunks,
//            global_load_lds staging, double-buffered (T3 minimum 2-phase) ----------
__global__ __launch_bounds__(256, 2)
void vq_main_kernel(const float* __restrict__ z,
                    const float* __restrict__ e,
                    const float* __restrict__ z2g,
                    const float* __restrict__ e2g,
                    float* __restrict__ out_zq,
                    float* __restrict__ out_idx,
                    double* __restrict__ partials) {
    __shared__ __align__(16) float Atile[2][BM * BK];   // 2 x 16 KiB
    __shared__ __align__(16) float Btile[2][BN * BK];   // 2 x 16 KiB
    __shared__ int    fIdx[BM];
    __shared__ double dred[256];

    const int tid  = threadIdx.x;
    const int m0   = blockIdx.x * BM;
    const int trow = tid >> 4;     // 0..15 -> rows trow*8..+8
    const int tcol = tid & 15;     // 0..15 -> cols tcol*8..+8
    const int keyA = trow & 7;
    const int keyB = tcol & 7;

    // staging lane mapping: lane covers (row = i*32 + rsub, physical chunk pc)
    const int rsub = tid >> 3;     // 0..31
    const int pc   = tid & 7;      // physical 16B chunk index within row

    int gA[4], gB[4];              // element offsets (row base + swizzled chunk)
#pragma unroll
    for (int i = 0; i < 4; ++i) {
        int r = i * 32 + rsub;                 // 0..127
        int l = pc ^ ((r >> 3) & 7);           // logical chunk at this physical slot
        gA[i] = (m0 + r) * EDIM + l * 4;
        gB[i] = r * EDIM + l * 4;              // + n0*EDIM + k0 at use
    }

    float z2r[8];
#pragma unroll
    for (int i = 0; i < 8; ++i) z2r[i] = z2g[m0 + trow * 8 + i];

    float bestV[8];
    int   bestI[8];
#pragma unroll
    for (int i = 0; i < 8; ++i) { bestV[i] = FLT_MAX; bestI[i] = 0; }

    // ---- prologue: stage tile 0 into buffer 0, drain, sync ----
#pragma unroll
    for (int i = 0; i < 4; ++i) {
        gload_lds16(z + gA[i], &Atile[0][(i * 256 + tid) * 4]);
        gload_lds16(e + gB[i], &Btile[0][(i * 256 + tid) * 4]);
    }
    asm volatile("s_waitcnt vmcnt(0)" ::: "memory");
    __syncthreads();

    float acc[8][8];

    // ---- main loop over 64 tiles: t -> (n0 = (t>>3)*BN, k0 = (t&7)*BK) ----
#pragma unroll 1
    for (int t = 0; t < 64; ++t) {
        const int cur = t & 1;

        // stage next tile u into the other buffer (u wraps 64->0: harmless dup)
        const int u   = (t + 1) & 63;
        const int n0u = (u >> 3) * BN;
        const int k0u = (u & 7) * BK;
        float* An = Atile[cur ^ 1];
        float* Bn = Btile[cur ^ 1];
#pragma unroll
        for (int i = 0; i < 4; ++i) {
            gload_lds16(z + gA[i] + k0u,                   &An[(i * 256 + tid) * 4]);
            gload_lds16(e + (n0u * EDIM) + gB[i] + k0u,    &Bn[(i * 256 + tid) * 4]);
        }

        if ((t & 7) == 0) {
#pragma unroll
            for (int i = 0; i < 8; ++i)
#pragma unroll
                for (int j = 0; j < 8; ++j) acc[i][j] = 0.f;
        }

        // compute on current buffer (loads for it were drained last iteration)
        const float* Ab = &Atile[cur][trow * (8 * BK)];
        const float* Bb = &Btile[cur][tcol * (8 * BK)];
#pragma unroll 2
        for (int kk = 0; kk < 8; ++kk) {       // 16B chunk = 4 consecutive k
            const float4* bp = reinterpret_cast<const float4*>(Bb + ((kk ^ keyB) << 2));
            float4 b[8];
#pragma unroll
            for (int j = 0; j < 8; ++j) b[j] = bp[j * 8];   // row stride 32 floats
            const float4* ap = reinterpret_cast<const float4*>(Ab + ((kk ^ keyA) << 2));
#pragma unroll
            for (int i = 0; i < 8; ++i) {
                float4 a = ap[i * 8];
#pragma unroll
                for (int j = 0; j < 8; ++j) {  // k ascending: x,y,z,w — chain preserved
                    acc[i][j] = __fmaf_rn(a.x, b[j].x, acc[i][j]);
                    acc[i][j] = __fmaf_rn(a.y, b[j].y, acc[i][j]);
                    acc[i][j] = __fmaf_rn(a.z, b[j].z, acc[i][j]);
                    acc[i][j] = __fmaf_rn(a.w, b[j].w, acc[i][j]);
                }
            }
        }

        if ((t & 7) == 7) {
            const int n0 = (t >> 3) * BN;
            float e2v[8];
            *reinterpret_cast<float4*>(&e2v[0]) =
                *reinterpret_cast<const float4*>(e2g + n0 + tcol * 8);
            *reinterpret_cast<float4*>(&e2v[4]) =
                *reinterpret_cast<const float4*>(e2g + n0 + tcol * 8 + 4);
            // d = fl(fl(z2 + e2) - 2*m); per-thread argmin, ascending col order
#pragma unroll
            for (int i = 0; i < 8; ++i) {
#pragma unroll
                for (int j = 0; j < 8; ++j) {
                    int   n = n0 + tcol * 8 + j;
                    float d = __fsub_rn(__fadd_rn(z2r[i], e2v[j]),
                                        __fmul_rn(2.0f, acc[i][j]));
                    if (d < bestV[i]) { bestV[i] = d; bestI[i] = n; }  // strict < keeps lowest idx
                }
            }
        }

        // drain next-tile loads (they had the whole compute phase to land), sync
        asm volatile("s_waitcnt vmcnt(0)" ::: "memory");
        __syncthreads();
    }

    // ---- merge 16 col-group threads per row via LDS (reuse tiles as scratch) ----
    float* red_v = Atile[0];                             // [BM][16] floats
    int*   red_i = reinterpret_cast<int*>(Btile[0]);     // [BM][16] ints
#pragma unroll
    for (int i = 0; i < 8; ++i) {
        int row = trow * 8 + i;
        red_v[row * 16 + tcol] = bestV[i];
        red_i[row * 16 + tcol] = bestI[i];
    }
    __syncthreads();

    if (tid < BM) {
        const int r = tid;
        float b1 = FLT_MAX; int i1 = 0x7fffffff;
        for (int tt = 0; tt < 16; ++tt) {
            float v  = red_v[r * 16 + tt];
            int   id = red_i[r * 16 + tt];
            if (v < b1 || (v == b1 && id < i1)) { b1 = v; i1 = id; }
        }
        fIdx[r] = i1;
        out_idx[m0 + r] = (float)i1;
    }
    __syncthreads();

    // ---- z_q_st write + loss partial ----
    double lsum = 0.0;
    for (int r = 0; r < BM; ++r) {
        int   fi = fIdx[r];
        float zv = z[(size_t)(m0 + r) * EDIM + tid];
        float ev = e[(size_t)fi * EDIM + tid];
        float dd = __fsub_rn(ev, zv);                                  // z_q - z (fp32)
        out_zq[(size_t)(m0 + r) * EDIM + tid] = __fadd_rn(zv, dd);     // z + sg(z_q - z)
        lsum += (double)dd * (double)dd;
    }
    dred[tid] = lsum;
    __syncthreads();
#pragma unroll
    for (int s = 128; s > 0; s >>= 1) {
        if (tid < s) dred[tid] += dred[tid + s];
        __syncthreads();
    }
    if (tid == 0) partials[blockIdx.x] = dred[0];
}

// ---------- loss finalize ----------
__global__ void vq_loss_kernel(const double* __restrict__ partials, float* __restrict__ out_loss) {
    __shared__ double s[256];
    const int tid = threadIdx.x;
    double v = 0.0;
    for (int i = tid; i < NROWS / BM; i += 256) v += partials[i];
    s[tid] = v;
    __syncthreads();
    for (int k = 128; k > 0; k >>= 1) {
        if (tid < k) s[tid] += s[tid + k];
        __syncthreads();
    }
    if (tid == 0) {
        double mean = s[0] / ((double)NROWS * (double)EDIM);
        out_loss[0] = (float)(1.25 * mean);   // (1 + BETA) * mean((z_q - z)^2)
    }
}

extern "C" void kernel_launch(void* const* d_in, const int* in_sizes, int n_in,
                              void* d_out, int out_size, void* d_ws, size_t ws_size,
                              hipStream_t stream) {
    (void)n_in; (void)out_size; (void)ws_size;
    const float* z = (const float*)d_in[0];
    const float* e = (const float*)d_in[1];
    if (in_sizes[0] == NE * EDIM) {           // defensive: swap if input order differs
        const float* t = z; z = e; e = t;
    }
    float* out      = (float*)d_out;
    float* out_zq   = out;
    float* out_loss = out + (size_t)NROWS * EDIM;
    float* out_idx  = out_loss + 1;

    float*  z2g      = (float*)d_ws;                          // 512 KiB
    float*  e2g      = (float*)((char*)d_ws + 524288);        // 4 KiB
    double* partials = (double*)((char*)d_ws + 532480);       // 8 KiB

    rownorm_kernel<<<(NROWS + 255) / 256, 256, 0, stream>>>(z, z2g, NROWS);
    rownorm_kernel<<<(NE + 255) / 256, 256, 0, stream>>>(e, e2g, NE);
    vq_main_kernel<<<NROWS / BM, 256, 0, stream>>>(z, e, z2g, e2g, out_zq, out_idx, partials);
    vq_loss_kernel<<<1, 256, 0, stream>>>(partials, out_loss);
}

// Round 6
// 1012.709 us; speedup vs baseline: 1.1214x; 1.0386x over previous
//
#include <hip/hip_runtime.h>
#include <cfloat>

#define NROWS 131072
#define EDIM 256
#define NE 1024

#define BM 128
#define BN 128
#define BK 32

// ---------- numpy pairwise sum-of-squares for one 256-elem contiguous row ----------
__device__ __forceinline__ float np_sumsq256(const float* __restrict__ row) {
    float s[2];
#pragma unroll
    for (int h = 0; h < 2; ++h) {
        const float* a = row + h * 128;
        float r[8];
#pragma unroll
        for (int j = 0; j < 8; ++j) r[j] = __fmul_rn(a[j], a[j]);
        for (int i = 8; i < 128; i += 8) {
#pragma unroll
            for (int j = 0; j < 8; ++j)
                r[j] = __fadd_rn(r[j], __fmul_rn(a[i + j], a[i + j]));
        }
        s[h] = __fadd_rn(__fadd_rn(__fadd_rn(r[0], r[1]), __fadd_rn(r[2], r[3])),
                         __fadd_rn(__fadd_rn(r[4], r[5]), __fadd_rn(r[6], r[7])));
    }
    return __fadd_rn(s[0], s[1]);
}

__global__ __launch_bounds__(256)
void rownorm_kernel(const float* __restrict__ x, float* __restrict__ out, int nrows) {
    int row = blockIdx.x * blockDim.x + threadIdx.x;
    if (row < nrows) out[row] = np_sumsq256(x + (size_t)row * EDIM);
}

// async global->LDS, 16B per lane, linear LDS dest (wave-uniform base + lane*16)
__device__ __forceinline__ void gload_lds16(const float* g, float* lds) {
    __builtin_amdgcn_global_load_lds((const __attribute__((address_space(1))) void*)g,
                                     (__attribute__((address_space(3))) void*)lds,
                                     16, 0, 0);
}

// ---------- main: sequential-FMA chain over k ascending (bit-exact vs round 3),
//            LDS row-major [row][BK] tiles, XOR-swizzled 16B chunks,
//            global_load_lds staging, SINGLE buffer -> 4 blocks/CU ----------
__global__ __launch_bounds__(256, 4)
void vq_main_kernel(const float* __restrict__ z,
                    const float* __restrict__ e,
                    const float* __restrict__ z2g,
                    const float* __restrict__ e2g,
                    float* __restrict__ out_zq,
                    float* __restrict__ out_idx,
                    double* __restrict__ partials) {
    __shared__ __align__(16) float Atile[BM * BK];   // 16 KiB
    __shared__ __align__(16) float Btile[BN * BK];   // 16 KiB
    __shared__ int    fIdx[BM];
    __shared__ double dred[256];

    const int tid  = threadIdx.x;
    const int m0   = blockIdx.x * BM;
    const int trow = tid >> 4;     // 0..15 -> rows trow*8..+8
    const int tcol = tid & 15;     // 0..15 -> cols tcol*8..+8
    const int keyA = trow & 7;
    const int keyB = tcol & 7;

    // staging lane mapping: lane covers (row = i*32 + rsub, physical chunk pc)
    const int rsub = tid >> 3;     // 0..31
    const int pc   = tid & 7;      // physical 16B chunk index within row

    int gA[4], gB[4];              // element offsets (row base + swizzled chunk)
#pragma unroll
    for (int i = 0; i < 4; ++i) {
        int r = i * 32 + rsub;                 // 0..127
        int l = pc ^ ((r >> 3) & 7);           // logical chunk at this physical slot
        gA[i] = (m0 + r) * EDIM + l * 4;
        gB[i] = r * EDIM + l * 4;              // + n0*EDIM + k0 at use
    }

    float z2r[8];
#pragma unroll
    for (int i = 0; i < 8; ++i) z2r[i] = z2g[m0 + trow * 8 + i];

    float bestV[8];
    int   bestI[8];
#pragma unroll
    for (int i = 0; i < 8; ++i) { bestV[i] = FLT_MAX; bestI[i] = 0; }

    float acc[8][8];

    // ---- main loop over 64 tiles: t -> (n0 = (t>>3)*BN, k0 = (t&7)*BK) ----
#pragma unroll 1
    for (int t = 0; t < 64; ++t) {
        const int n0 = (t >> 3) * BN;
        const int k0 = (t & 7) * BK;

        __syncthreads();                       // previous tile's readers done
#pragma unroll
        for (int i = 0; i < 4; ++i) {
            gload_lds16(z + gA[i] + k0,                &Atile[(i * 256 + tid) * 4]);
            gload_lds16(e + (n0 * EDIM) + gB[i] + k0,  &Btile[(i * 256 + tid) * 4]);
        }

        if ((t & 7) == 0) {
#pragma unroll
            for (int i = 0; i < 8; ++i)
#pragma unroll
                for (int j = 0; j < 8; ++j) acc[i][j] = 0.f;
        }

        asm volatile("s_waitcnt vmcnt(0)" ::: "memory");
        __syncthreads();                       // tile visible to all waves

        const float* Ab = &Atile[trow * (8 * BK)];
        const float* Bb = &Btile[tcol * (8 * BK)];
#pragma unroll 2
        for (int kk = 0; kk < 8; ++kk) {       // 16B chunk = 4 consecutive k
            const float4* bp = reinterpret_cast<const float4*>(Bb + ((kk ^ keyB) << 2));
            float4 b[8];
#pragma unroll
            for (int j = 0; j < 8; ++j) b[j] = bp[j * 8];   // row stride 32 floats
            const float4* ap = reinterpret_cast<const float4*>(Ab + ((kk ^ keyA) << 2));
#pragma unroll
            for (int i = 0; i < 8; ++i) {
                float4 a = ap[i * 8];
#pragma unroll
                for (int j = 0; j < 8; ++j) {  // k ascending: x,y,z,w — chain preserved
                    acc[i][j] = __fmaf_rn(a.x, b[j].x, acc[i][j]);
                    acc[i][j] = __fmaf_rn(a.y, b[j].y, acc[i][j]);
                    acc[i][j] = __fmaf_rn(a.z, b[j].z, acc[i][j]);
                    acc[i][j] = __fmaf_rn(a.w, b[j].w, acc[i][j]);
                }
            }
        }

        if ((t & 7) == 7) {
            float e2v[8];
            *reinterpret_cast<float4*>(&e2v[0]) =
                *reinterpret_cast<const float4*>(e2g + n0 + tcol * 8);
            *reinterpret_cast<float4*>(&e2v[4]) =
                *reinterpret_cast<const float4*>(e2g + n0 + tcol * 8 + 4);
            // d = fl(fl(z2 + e2) - 2*m); per-thread argmin, ascending col order
#pragma unroll
            for (int i = 0; i < 8; ++i) {
#pragma unroll
                for (int j = 0; j < 8; ++j) {
                    int   n = n0 + tcol * 8 + j;
                    float d = __fsub_rn(__fadd_rn(z2r[i], e2v[j]),
                                        __fmul_rn(2.0f, acc[i][j]));
                    if (d < bestV[i]) { bestV[i] = d; bestI[i] = n; }  // strict < keeps lowest idx
                }
            }
        }
    }

    // ---- merge 16 col-group threads per row via LDS (reuse tiles as scratch) ----
    __syncthreads();
    float* red_v = Atile;                             // [BM][16] floats
    int*   red_i = reinterpret_cast<int*>(Btile);     // [BM][16] ints
#pragma unroll
    for (int i = 0; i < 8; ++i) {
        int row = trow * 8 + i;
        red_v[row * 16 + tcol] = bestV[i];
        red_i[row * 16 + tcol] = bestI[i];
    }
    __syncthreads();

    if (tid < BM) {
        const int r = tid;
        float b1 = FLT_MAX; int i1 = 0x7fffffff;
        for (int tt = 0; tt < 16; ++tt) {
            float v  = red_v[r * 16 + tt];
            int   id = red_i[r * 16 + tt];
            if (v < b1 || (v == b1 && id < i1)) { b1 = v; i1 = id; }
        }
        fIdx[r] = i1;
        out_idx[m0 + r] = (float)i1;
    }
    __syncthreads();

    // ---- z_q_st write + loss partial ----
    double lsum = 0.0;
    for (int r = 0; r < BM; ++r) {
        int   fi = fIdx[r];
        float zv = z[(size_t)(m0 + r) * EDIM + tid];
        float ev = e[(size_t)fi * EDIM + tid];
        float dd = __fsub_rn(ev, zv);                                  // z_q - z (fp32)
        out_zq[(size_t)(m0 + r) * EDIM + tid] = __fadd_rn(zv, dd);     // z + sg(z_q - z)
        lsum += (double)dd * (double)dd;
    }
    dred[tid] = lsum;
    __syncthreads();
#pragma unroll
    for (int s = 128; s > 0; s >>= 1) {
        if (tid < s) dred[tid] += dred[tid + s];
        __syncthreads();
    }
    if (tid == 0) partials[blockIdx.x] = dred[0];
}

// ---------- loss finalize ----------
__global__ void vq_loss_kernel(const double* __restrict__ partials, float* __restrict__ out_loss) {
    __shared__ double s[256];
    const int tid = threadIdx.x;
    double v = 0.0;
    for (int i = tid; i < NROWS / BM; i += 256) v += partials[i];
    s[tid] = v;
    __syncthreads();
    for (int k = 128; k > 0; k >>= 1) {
        if (tid < k) s[tid] += s[tid + k];
        __syncthreads();
    }
    if (tid == 0) {
        double mean = s[0] / ((double)NROWS * (double)EDIM);
        out_loss[0] = (float)(1.25 * mean);   // (1 + BETA) * mean((z_q - z)^2)
    }
}

extern "C" void kernel_launch(void* const* d_in, const int* in_sizes, int n_in,
                              void* d_out, int out_size, void* d_ws, size_t ws_size,
                              hipStream_t stream) {
    (void)n_in; (void)out_size; (void)ws_size;
    const float* z = (const float*)d_in[0];
    const float* e = (const float*)d_in[1];
    if (in_sizes[0] == NE * EDIM) {           // defensive: swap if input order differs
        const float* t = z; z = e; e = t;
    }
    float* out      = (float*)d_out;
    float* out_zq   = out;
    float* out_loss = out + (size_t)NROWS * EDIM;
    float* out_idx  = out_loss + 1;

    float*  z2g      = (float*)d_ws;                          // 512 KiB
    float*  e2g      = (float*)((char*)d_ws + 524288);        // 4 KiB
    double* partials = (double*)((char*)d_ws + 532480);       // 8 KiB

    rownorm_kernel<<<(NROWS + 255) / 256, 256, 0, stream>>>(z, z2g, NROWS);
    rownorm_kernel<<<(NE + 255) / 256, 256, 0, stream>>>(e, e2g, NE);
    vq_main_kernel<<<NROWS / BM, 256, 0, stream>>>(z, e, z2g, e2g, out_zq, out_idx, partials);
    vq_loss_kernel<<<1, 256, 0, stream>>>(partials, out_loss);
}